// Round 1
// baseline (1168.729 us; speedup 1.0000x reference)
//
#include <hip/hip_runtime.h>

#define NB 256   // batch
#define NS 256   // seq len == number of steps
#define NE 2     // encoder dim
#define ND 128   // decoder dim
#define NT 512   // threads per block (8 waves)

constexpr float L2E = 1.4426950408889634f;  // log2(e)

// One block per batch element. The full 256-step recurrence runs inside the
// block (batch elements are independent; no grid sync needed).
// Each thread owns one W_hh gate row in 128 VGPRs (streaming from L2 every
// step would cost ~17 TB — at the L2 ceiling).
__global__ __launch_bounds__(NT, 2)
void attn_lstm_decoder(const float* __restrict__ enc,   // [B,S,E]
                       const float* __restrict__ W1w,   // [S,S]
                       const float* __restrict__ W1b,   // [S]
                       const float* __restrict__ W2w,   // [S,2S]
                       const float* __restrict__ W2b,   // [S]
                       const float* __restrict__ Wih,   // [4D,E]
                       const float* __restrict__ Whh,   // [4D,D]
                       const float* __restrict__ bih,   // [4D]
                       const float* __restrict__ bhh,   // [4D]
                       float* __restrict__ out)         // [S,B,D]
{
    const int b    = blockIdx.x;
    const int t    = threadIdx.x;
    const int wave = t >> 6;
    const int lane = t & 63;
    const int grp  = lane >> 4;   // 4 row-groups of 16 lanes: 4 d-rows in parallel
    const int lj   = lane & 15;   // lane-in-group: owns s = lj + 16k, k=0..15

    __shared__ __align__(16) float h_lds[ND];
    __shared__ float gbuf[4 * ND];
    __shared__ float ctxbuf[16];      // 8 waves x {p0,p1} partial context
    __shared__ float A2_l[NS];        // 2*log2e*(w2term + W2_b + W1_b)
    __shared__ float g2_l[NS];        // 2*log2e*w1sum
    __shared__ float e0_l[NS];        // enc[b,s,0]
    __shared__ float e1_l[NS];        // enc[b,s,1]

    // ---------------- setup (once per block) ----------------
    {
        float v = enc[b * (NS * NE) + t];      // coalesced, t in [0,512)
        if (t & 1) e1_l[t >> 1] = v; else e0_l[t >> 1] = v;
    }
    __syncthreads();

    // w1sum rows and w2term rows: 32 rows per wave, coalesced column reads.
    for (int r = 0; r < 32; ++r) {
        const int s = wave * 32 + r;
        // w1sum[s] = sum_j W1_w[s,j]
        float p = W1w[s * NS + lane]       + W1w[s * NS + lane + 64]
                + W1w[s * NS + lane + 128] + W1w[s * NS + lane + 192];
        #pragma unroll
        for (int m = 32; m >= 1; m >>= 1) p += __shfl_xor(p, m);
        if (lane == 0) g2_l[s] = p * (2.0f * L2E);
        // w2term[s] = dot(enc_flat, W2_w[s,:]) over 512
        float q = 0.0f;
        #pragma unroll
        for (int kk = 0; kk < 8; ++kk) {
            const int c = lane + kk * 64;
            const float ev = (c & 1) ? e1_l[c >> 1] : e0_l[c >> 1];
            q = fmaf(ev, W2w[s * (2 * NS) + c], q);
        }
        #pragma unroll
        for (int m = 32; m >= 1; m >>= 1) q += __shfl_xor(q, m);
        if (lane == 0) A2_l[s] = (q + W2b[s] + W1b[s]) * (2.0f * L2E);
    }

    // W_hh row t -> 128 VGPRs (one-time, L2-served)
    float4 wr[32];
    {
        const float4* W4 = reinterpret_cast<const float4*>(Whh + t * ND);
        #pragma unroll
        for (int qi = 0; qi < 32; ++qi) wr[qi] = W4[qi];
    }
    const float wi0  = Wih[t * 2 + 0];
    const float wi1  = Wih[t * 2 + 1];
    const float bias = bih[t] + bhh[t];

    if (t < ND) h_lds[t] = 0.0f;
    float c_reg = 0.0f;
    __syncthreads();

    // per-lane step-invariant caches (s = lj + 16k)
    float A2r[16], g2r[16], E0r[16], E1r[16];
    #pragma unroll
    for (int k = 0; k < 16; ++k) {
        const int s = k * 16 + lj;
        A2r[k] = A2_l[s];
        g2r[k] = g2_l[s];
        E0r[k] = e0_l[s];
        E1r[k] = e1_l[s];
    }

    const float C2 = -2.0f * L2E;

    // ---------------- the recurrence ----------------
    for (int step = 0; step < NS; ++step) {
        // Phase A: attention. en = tanh(x) in [-1,1] => softmax needs no
        // max-subtract. alpha never materialized: ctx = (1/D) sum_d p(d)/l(d).
        float ctx0 = 0.0f, ctx1 = 0.0f;
        #pragma unroll
        for (int r = 0; r < 4; ++r) {
            const int d = wave * 16 + r * 4 + grp;
            const float hd = h_lds[d];                 // LDS broadcast
            float l = 0.0f, p0 = 0.0f, p1 = 0.0f;
            #pragma unroll
            for (int k = 0; k < 16; ++k) {
                // e = exp(tanh(x)), x = A + hd*g:
                //   u = 2^(2*L2E*x); rc = 1/(u+1); e = 2^(L2E - 2*L2E*rc)
                float m1 = fmaf(hd, g2r[k], A2r[k]);
                float u  = __builtin_amdgcn_exp2f(m1);
                float rc = __builtin_amdgcn_rcpf(u + 1.0f);
                float m2 = fmaf(rc, C2, L2E);
                float e  = __builtin_amdgcn_exp2f(m2);
                l += e;
                p0 = fmaf(e, E0r[k], p0);
                p1 = fmaf(e, E1r[k], p1);
            }
            #pragma unroll
            for (int m = 8; m >= 1; m >>= 1) {         // 16-lane butterfly
                l  += __shfl_xor(l, m);
                p0 += __shfl_xor(p0, m);
                p1 += __shfl_xor(p1, m);
            }
            const float rl = __builtin_amdgcn_rcpf(l);
            ctx0 = fmaf(p0, rl, ctx0);
            ctx1 = fmaf(p1, rl, ctx1);
        }
        // combine the 4 row-groups, then one write per wave
        ctx0 += __shfl_xor(ctx0, 16);  ctx0 += __shfl_xor(ctx0, 32);
        ctx1 += __shfl_xor(ctx1, 16);  ctx1 += __shfl_xor(ctx1, 32);
        if (lane == 0) {
            ctxbuf[wave * 2 + 0] = ctx0;
            ctxbuf[wave * 2 + 1] = ctx1;
        }
        __syncthreads();

        float x0 = 0.0f, x1 = 0.0f;
        #pragma unroll
        for (int w = 0; w < 8; ++w) { x0 += ctxbuf[w * 2]; x1 += ctxbuf[w * 2 + 1]; }
        x0 *= (1.0f / ND);
        x1 *= (1.0f / ND);

        // Phase B: gates[t] = x@W_ih[t,:] + h . W_hh[t,:] + bias
        float acc = fmaf(x0, wi0, fmaf(x1, wi1, bias));
        const float4* h4 = reinterpret_cast<const float4*>(h_lds);
        #pragma unroll
        for (int qi = 0; qi < 32; ++qi) {
            const float4 hv = h4[qi];                  // ds_read_b128 broadcast
            acc = fmaf(wr[qi].x, hv.x, acc);
            acc = fmaf(wr[qi].y, hv.y, acc);
            acc = fmaf(wr[qi].z, hv.z, acc);
            acc = fmaf(wr[qi].w, hv.w, acc);
        }
        gbuf[t] = acc;
        __syncthreads();

        // Phase C: LSTM pointwise update (threads 0..127 own c[d])
        if (t < ND) {
            const float gi = gbuf[t];
            const float gf = gbuf[ND + t];
            const float gg = gbuf[2 * ND + t];
            const float go = gbuf[3 * ND + t];
            const float si = __builtin_amdgcn_rcpf(1.0f + __builtin_amdgcn_exp2f(-L2E * gi));
            const float sf = __builtin_amdgcn_rcpf(1.0f + __builtin_amdgcn_exp2f(-L2E * gf));
            const float so = __builtin_amdgcn_rcpf(1.0f + __builtin_amdgcn_exp2f(-L2E * go));
            const float tg = 1.0f - 2.0f * __builtin_amdgcn_rcpf(__builtin_amdgcn_exp2f(2.0f * L2E * gg) + 1.0f);
            c_reg = sf * c_reg + si * tg;
            const float tc = 1.0f - 2.0f * __builtin_amdgcn_rcpf(__builtin_amdgcn_exp2f(2.0f * L2E * c_reg) + 1.0f);
            const float hn = so * tc;
            h_lds[t] = hn;
            out[step * (NB * ND) + b * ND + t] = hn;   // [S,B,D]
        }
        __syncthreads();
    }
}

extern "C" void kernel_launch(void* const* d_in, const int* in_sizes, int n_in,
                              void* d_out, int out_size, void* d_ws, size_t ws_size,
                              hipStream_t stream) {
    const float* enc = (const float*)d_in[0];
    const float* W1w = (const float*)d_in[1];
    const float* W1b = (const float*)d_in[2];
    const float* W2w = (const float*)d_in[3];
    const float* W2b = (const float*)d_in[4];
    const float* Wih = (const float*)d_in[5];
    const float* Whh = (const float*)d_in[6];
    const float* bih = (const float*)d_in[7];
    const float* bhh = (const float*)d_in[8];
    attn_lstm_decoder<<<NB, NT, 0, stream>>>(enc, W1w, W1b, W2w, W2b,
                                             Wih, Whh, bih, bhh, (float*)d_out);
}

// Round 2
// 713.725 us; speedup vs baseline: 1.6375x; 1.6375x over previous
//
#include <hip/hip_runtime.h>

#define NB 256   // batch
#define NS 256   // seq len == number of steps
#define NE 2     // encoder dim
#define ND 128   // decoder dim
#define NT 512   // threads per block (8 waves)
#define NN 16    // Chebyshev nodes for the h -> context map

constexpr float L2E = 1.4426950408889634f;  // log2(e)
constexpr float PI_F = 3.14159265358979323846f;

// One block per batch element; full 256-step recurrence inside the block.
// Attention trick: ctx = mean_d F(h_d), F(h) = sum_s softmax_s(tanh(A_s + h*g_s)) enc_s.
// F is analytic on |h|<1 (nearest tanh pole at Im h ~ (pi/2)/|g|max ~ 0.9), so a
// degree-15 Chebyshev interpolant is exact to ~1e-5. Evaluate the softmax at 16
// nodes only (8x fewer transcendentals than 128 d-values); recover the exact
// d-mean of the interpolant via Chebyshev moments t_i = mean_d T_i(h_d).
__global__ __launch_bounds__(NT, 2)
void attn_lstm_decoder(const float* __restrict__ enc,   // [B,S,E]
                       const float* __restrict__ W1w,   // [S,S]
                       const float* __restrict__ W1b,   // [S]
                       const float* __restrict__ W2w,   // [S,2S]
                       const float* __restrict__ W2b,   // [S]
                       const float* __restrict__ Wih,   // [4D,E]
                       const float* __restrict__ Whh,   // [4D,D]
                       const float* __restrict__ bih,   // [4D]
                       const float* __restrict__ bhh,   // [4D]
                       float* __restrict__ out)         // [S,B,D]
{
    const int b    = blockIdx.x;
    const int t    = threadIdx.x;
    const int wave = t >> 6;
    const int lane = t & 63;
    const int half = lane >> 5;       // node j = 2*wave + half
    const int idx  = lane & 31;       // lane-in-node: owns s = idx + 32k, k=0..7
    const int jnode = 2 * wave + half;

    __shared__ __align__(16) float h_lds[ND];
    __shared__ float gbuf[4 * ND];
    __shared__ float2 ctx2[NN];       // per-node weighted partial context
    __shared__ float A2_l[NS];        // 2*log2e*(w2term + W2_b + W1_b)
    __shared__ float g2_l[NS];        // 2*log2e*w1sum
    __shared__ float e0_l[NS];        // enc[b,s,0]
    __shared__ float e1_l[NS];        // enc[b,s,1]
    __shared__ float Ml[NN * NN];     // DCT-II-ish: M[i][j], c_i = sum_j M[i][j] f_j
    __shared__ float tbar[NN];        // Chebyshev moments of {h_d}

    // ---------------- setup (once per block) ----------------
    {
        float v = enc[b * (NS * NE) + t];      // coalesced
        if (t & 1) e1_l[t >> 1] = v; else e0_l[t >> 1] = v;
    }
    if (t < NN * NN) {
        const int mi = t >> 4, mj = t & 15;
        const float w = (mi == 0) ? (1.0f / NN) : (2.0f / NN);
        Ml[t] = w * __cosf((float)(mi * (2 * mj + 1)) * (PI_F / (2 * NN)));
    }
    __syncthreads();

    // w1sum rows and w2term rows: 32 rows per wave, coalesced column reads.
    for (int r = 0; r < 32; ++r) {
        const int s = wave * 32 + r;
        float p = W1w[s * NS + lane]       + W1w[s * NS + lane + 64]
                + W1w[s * NS + lane + 128] + W1w[s * NS + lane + 192];
        #pragma unroll
        for (int m = 32; m >= 1; m >>= 1) p += __shfl_xor(p, m);
        if (lane == 0) g2_l[s] = p * (2.0f * L2E);
        float q = 0.0f;
        #pragma unroll
        for (int kk = 0; kk < 8; ++kk) {
            const int c = lane + kk * 64;
            const float ev = (c & 1) ? e1_l[c >> 1] : e0_l[c >> 1];
            q = fmaf(ev, W2w[s * (2 * NS) + c], q);
        }
        #pragma unroll
        for (int m = 32; m >= 1; m >>= 1) q += __shfl_xor(q, m);
        if (lane == 0) A2_l[s] = (q + W2b[s] + W1b[s]) * (2.0f * L2E);
    }

    // W_hh row t -> 128 VGPRs (one-time, L2-served)
    float4 wr[32];
    {
        const float4* W4 = reinterpret_cast<const float4*>(Whh + t * ND);
        #pragma unroll
        for (int qi = 0; qi < 32; ++qi) wr[qi] = W4[qi];
    }
    const float wi0  = Wih[t * 2 + 0];
    const float wi1  = Wih[t * 2 + 1];
    const float bias = bih[t] + bhh[t];

    if (t < ND) h_lds[t] = 0.0f;
    float c_reg = 0.0f;
    __syncthreads();

    // per-lane step-invariant caches for this node's s-slice (s = idx + 32k)
    float A2r[8], g2r[8], E0r[8], E1r[8];
    #pragma unroll
    for (int k = 0; k < 8; ++k) {
        const int s = k * 32 + idx;
        A2r[k] = A2_l[s];
        g2r[k] = g2_l[s];
        E0r[k] = e0_l[s];
        E1r[k] = e1_l[s];
    }
    const float ynode = __cosf((float)(2 * jnode + 1) * (PI_F / (2 * NN)));
    const float C2 = -2.0f * L2E;

    // ---------------- the recurrence ----------------
    for (int step = 0; step < NS; ++step) {
        // Phase M: Chebyshev moments tbar[i] = mean_d T_i(h_d).
        // i = t>>5 (16 groups of 32 lanes); each lane covers 4 d-values.
        {
            const int mi = jnode;  // reuse: group index 0..15
            const float hm0 = h_lds[idx], hm1 = h_lds[idx + 32];
            const float hm2 = h_lds[idx + 64], hm3 = h_lds[idx + 96];
            float sred;
            if (mi == 0) {
                sred = 4.0f;
            } else {
                float a0 = hm0, a1 = hm1, a2 = hm2, a3 = hm3;   // T1
                float p0 = 1.0f, p1 = 1.0f, p2 = 1.0f, p3 = 1.0f; // T0
                const float d0 = hm0 + hm0, d1 = hm1 + hm1;
                const float d2 = hm2 + hm2, d3 = hm3 + hm3;
                for (int n = 2; n <= mi; ++n) {
                    const float t0 = fmaf(d0, a0, -p0);
                    const float t1 = fmaf(d1, a1, -p1);
                    const float t2 = fmaf(d2, a2, -p2);
                    const float t3 = fmaf(d3, a3, -p3);
                    p0 = a0; p1 = a1; p2 = a2; p3 = a3;
                    a0 = t0; a1 = t1; a2 = t2; a3 = t3;
                }
                sred = a0 + a1 + a2 + a3;
            }
            #pragma unroll
            for (int m = 1; m <= 16; m <<= 1) sred += __shfl_xor(sred, m);
            if (idx == 0) tbar[mi] = sred * (1.0f / ND);
        }

        // Phase A: softmax at this thread's Chebyshev node (no barrier needed
        // before this — it is independent of tbar/h).
        float l = 0.0f, p0 = 0.0f, p1 = 0.0f;
        #pragma unroll
        for (int k = 0; k < 8; ++k) {
            // e ~ exp(tanh(x)) up to a per-node-uniform factor (cancels in p/l):
            //   u = e^{2x} = 2^(A2 + y*g2); rc = 1/(u+1); e = 2^(-2*log2e*rc)
            const float m1 = fmaf(ynode, g2r[k], A2r[k]);
            const float u  = __builtin_amdgcn_exp2f(m1);
            const float rc = __builtin_amdgcn_rcpf(u + 1.0f);
            const float e  = __builtin_amdgcn_exp2f(rc * C2);
            l += e;
            p0 = fmaf(e, E0r[k], p0);
            p1 = fmaf(e, E1r[k], p1);
        }
        #pragma unroll
        for (int m = 1; m <= 16; m <<= 1) {        // reduce within the 32-lane node
            l  += __shfl_xor(l, m);
            p0 += __shfl_xor(p0, m);
            p1 += __shfl_xor(p1, m);
        }
        __syncthreads();   // B1: tbar visible everywhere

        if (idx == 0) {
            // u_j = sum_i M[i][j] * tbar[i]  (Lagrange-mean weight for this node)
            float uj = 0.0f;
            #pragma unroll
            for (int i = 0; i < NN; ++i) uj = fmaf(Ml[i * NN + jnode], tbar[i], uj);
            const float rl = __builtin_amdgcn_rcpf(l);
            const float w  = uj * rl;
            ctx2[jnode] = make_float2(p0 * w, p1 * w);
        }
        __syncthreads();   // B2: ctx2 ready

        float x0 = 0.0f, x1 = 0.0f;
        #pragma unroll
        for (int n = 0; n < NN; ++n) { const float2 v = ctx2[n]; x0 += v.x; x1 += v.y; }

        // Phase B: gates[t] = x@W_ih[t,:] + h . W_hh[t,:] + bias
        float acc = fmaf(x0, wi0, fmaf(x1, wi1, bias));
        const float4* h4 = reinterpret_cast<const float4*>(h_lds);
        #pragma unroll
        for (int qi = 0; qi < 32; ++qi) {
            const float4 hv = h4[qi];                  // ds_read_b128 broadcast
            acc = fmaf(wr[qi].x, hv.x, acc);
            acc = fmaf(wr[qi].y, hv.y, acc);
            acc = fmaf(wr[qi].z, hv.z, acc);
            acc = fmaf(wr[qi].w, hv.w, acc);
        }
        gbuf[t] = acc;
        __syncthreads();   // B3: gates ready

        // Phase C: LSTM pointwise update (threads 0..127 own c[d])
        if (t < ND) {
            const float gi = gbuf[t];
            const float gf = gbuf[ND + t];
            const float gg = gbuf[2 * ND + t];
            const float go = gbuf[3 * ND + t];
            const float si = __builtin_amdgcn_rcpf(1.0f + __builtin_amdgcn_exp2f(-L2E * gi));
            const float sf = __builtin_amdgcn_rcpf(1.0f + __builtin_amdgcn_exp2f(-L2E * gf));
            const float so = __builtin_amdgcn_rcpf(1.0f + __builtin_amdgcn_exp2f(-L2E * go));
            const float tg = 1.0f - 2.0f * __builtin_amdgcn_rcpf(__builtin_amdgcn_exp2f(2.0f * L2E * gg) + 1.0f);
            c_reg = sf * c_reg + si * tg;
            const float tc = 1.0f - 2.0f * __builtin_amdgcn_rcpf(__builtin_amdgcn_exp2f(2.0f * L2E * c_reg) + 1.0f);
            const float hn = so * tc;
            h_lds[t] = hn;
            out[step * (NB * ND) + b * ND + t] = hn;   // [S,B,D]
        }
        __syncthreads();   // B4: h ready for next step's moments
    }
}

extern "C" void kernel_launch(void* const* d_in, const int* in_sizes, int n_in,
                              void* d_out, int out_size, void* d_ws, size_t ws_size,
                              hipStream_t stream) {
    const float* enc = (const float*)d_in[0];
    const float* W1w = (const float*)d_in[1];
    const float* W1b = (const float*)d_in[2];
    const float* W2w = (const float*)d_in[3];
    const float* W2b = (const float*)d_in[4];
    const float* Wih = (const float*)d_in[5];
    const float* Whh = (const float*)d_in[6];
    const float* bih = (const float*)d_in[7];
    const float* bhh = (const float*)d_in[8];
    attn_lstm_decoder<<<NB, NT, 0, stream>>>(enc, W1w, W1b, W2w, W2b,
                                             Wih, Whh, bih, bhh, (float*)d_out);
}

// Round 3
// 388.938 us; speedup vs baseline: 3.0049x; 1.8351x over previous
//
#include <hip/hip_runtime.h>

#define NB 256   // batch
#define NS 256   // seq len == number of steps
#define NE 2     // encoder dim
#define ND 128   // decoder dim
#define NT 512   // threads per block (8 waves)
#define NN 16    // Chebyshev nodes/degree for the h -> context map

typedef float vf4 __attribute__((ext_vector_type(4)));

constexpr float L2E = 1.4426950408889634f;  // log2(e)
constexpr float PI_F = 3.14159265358979323846f;

// One block per batch element; full 256-step recurrence inside the block.
//
// Attention collapse: ctx = mean_d F(h_d), F(h) = sum_s softmax_s(tanh(A_s+h*g_s)) enc_s.
// F is step-invariant and analytic on |h|<1  => evaluate F at 16 Chebyshev nodes ONCE
// (setup), DCT to Chebyshev coefficients V[i] (with 1/D folded in). Per step the whole
// attention is x_e = sum_d G_e(h_d), G_e(h) = sum_i V_e[i] T_i(h): a degree-15
// polynomial evaluated by the 128 threads that already hold h_d in registers.
__global__ __launch_bounds__(NT, 2)
void attn_lstm_decoder(const float* __restrict__ enc,   // [B,S,E]
                       const float* __restrict__ W1w,   // [S,S]
                       const float* __restrict__ W1b,   // [S]
                       const float* __restrict__ W2w,   // [S,2S]
                       const float* __restrict__ W2b,   // [S]
                       const float* __restrict__ Wih,   // [4D,E]
                       const float* __restrict__ Whh,   // [4D,D]
                       const float* __restrict__ bih,   // [4D]
                       const float* __restrict__ bhh,   // [4D]
                       float* __restrict__ out)         // [S,B,D]
{
    const int b    = blockIdx.x;
    const int t    = threadIdx.x;
    const int wave = t >> 6;
    const int lane = t & 63;
    const int half = lane >> 5;       // node j = 2*wave + half (setup only)
    const int idx  = lane & 31;       // lane-in-node (setup only)
    const int jnode = 2 * wave + half;

    __shared__ __align__(16) float h_lds[ND];
    __shared__ float gbuf[4 * ND];
    __shared__ float A2_l[NS];        // 2*log2e*(w2term + W2_b + W1_b)
    __shared__ float g2_l[NS];        // 2*log2e*w1sum
    __shared__ float e0_l[NS];        // enc[b,s,0]
    __shared__ float e1_l[NS];        // enc[b,s,1]
    __shared__ float Ml[NN * NN];     // DCT: c_i = sum_j M[i][j] F(y_j)
    __shared__ float2 Pn[NN];         // F(y_j) = (p0/l, p1/l) per node
    __shared__ float2 Vl[NN];         // Chebyshev coeffs of F, with 1/ND folded in
    __shared__ float2 xpart[2];       // per-wave partial of sum_d G(h_d)

    // ---------------- setup (once per block) ----------------
    {
        float v = enc[b * (NS * NE) + t];      // coalesced
        if (t & 1) e1_l[t >> 1] = v; else e0_l[t >> 1] = v;
    }
    if (t < NN * NN) {
        const int mi = t >> 4, mj = t & 15;
        const float w = (mi == 0) ? (1.0f / NN) : (2.0f / NN);
        Ml[t] = w * __cosf((float)(mi * (2 * mj + 1)) * (PI_F / (2 * NN)));
    }
    __syncthreads();

    // w1sum rows and w2term rows: 32 rows per wave, coalesced column reads.
    for (int r = 0; r < 32; ++r) {
        const int s = wave * 32 + r;
        float p = W1w[s * NS + lane]       + W1w[s * NS + lane + 64]
                + W1w[s * NS + lane + 128] + W1w[s * NS + lane + 192];
        #pragma unroll
        for (int m = 32; m >= 1; m >>= 1) p += __shfl_xor(p, m);
        if (lane == 0) g2_l[s] = p * (2.0f * L2E);
        float q = 0.0f;
        #pragma unroll
        for (int kk = 0; kk < 8; ++kk) {
            const int c = lane + kk * 64;
            const float ev = (c & 1) ? e1_l[c >> 1] : e0_l[c >> 1];
            q = fmaf(ev, W2w[s * (2 * NS) + c], q);
        }
        #pragma unroll
        for (int m = 32; m >= 1; m >>= 1) q += __shfl_xor(q, m);
        if (lane == 0) A2_l[s] = (q + W2b[s] + W1b[s]) * (2.0f * L2E);
    }
    __syncthreads();

    // One-time node softmax: F(y_j) for the 16 Chebyshev nodes.
    {
        const float y  = __cosf((float)(2 * jnode + 1) * (PI_F / (2 * NN)));
        const float C2 = -2.0f * L2E;
        float l = 0.0f, p0 = 0.0f, p1 = 0.0f;
        #pragma unroll
        for (int k = 0; k < 8; ++k) {
            const int s = k * 32 + idx;
            // e ~ exp(tanh(x)) up to a per-node-uniform factor (cancels in p/l)
            const float m1 = fmaf(y, g2_l[s], A2_l[s]);
            const float u  = __builtin_amdgcn_exp2f(m1);
            const float rc = __builtin_amdgcn_rcpf(u + 1.0f);
            const float e  = __builtin_amdgcn_exp2f(rc * C2);
            l += e;
            p0 = fmaf(e, e0_l[s], p0);
            p1 = fmaf(e, e1_l[s], p1);
        }
        #pragma unroll
        for (int m = 1; m <= 16; m <<= 1) {
            l  += __shfl_xor(l, m);
            p0 += __shfl_xor(p0, m);
            p1 += __shfl_xor(p1, m);
        }
        if (idx == 0) {
            const float rl = __builtin_amdgcn_rcpf(l);
            Pn[jnode] = make_float2(p0 * rl, p1 * rl);
        }
    }
    __syncthreads();

    // DCT collapse: V[i] = sum_j M[i][j] * Pn[j], with 1/ND folded in.
    if (t < NN) {
        float v0 = 0.0f, v1 = 0.0f;
        #pragma unroll
        for (int j = 0; j < NN; ++j) {
            v0 = fmaf(Ml[t * NN + j], Pn[j].x, v0);
            v1 = fmaf(Ml[t * NN + j], Pn[j].y, v1);
        }
        Vl[t] = make_float2(v0 * (1.0f / ND), v1 * (1.0f / ND));
    }

    // W_hh row t -> registers (one-time, L2-served)
    vf4 wr[32];
    {
        const vf4* W4 = reinterpret_cast<const vf4*>(Whh + t * ND);
        #pragma unroll
        for (int qi = 0; qi < 32; ++qi) wr[qi] = W4[qi];
    }
    const float wi0  = Wih[t * 2 + 0];
    const float wi1  = Wih[t * 2 + 1];
    const float bias = bih[t] + bhh[t];

    if (t < ND) h_lds[t] = 0.0f;
    float c_reg = 0.0f, h_reg = 0.0f;
    __syncthreads();

    float V0r[NN], V1r[NN];
    #pragma unroll
    for (int i = 0; i < NN; ++i) { V0r[i] = Vl[i].x; V1r[i] = Vl[i].y; }

    // ---------------- the recurrence (2 barriers per step) ----------------
    for (int step = 0; step < NS; ++step) {
        // Phase G: x = sum_d G(h_d); threads t<128 hold h_d in h_reg.
        if (t < ND) {
            float acc0 = fmaf(V0r[1], h_reg, V0r[0]);
            float acc1 = fmaf(V1r[1], h_reg, V1r[0]);
            float tp = 1.0f, tc = h_reg;
            const float h2 = h_reg + h_reg;
            #pragma unroll
            for (int i = 2; i < NN; ++i) {
                const float tn = fmaf(h2, tc, -tp);
                acc0 = fmaf(V0r[i], tn, acc0);
                acc1 = fmaf(V1r[i], tn, acc1);
                tp = tc; tc = tn;
            }
            #pragma unroll
            for (int m = 1; m <= 32; m <<= 1) {
                acc0 += __shfl_xor(acc0, m);
                acc1 += __shfl_xor(acc1, m);
            }
            if (lane == 0) xpart[wave] = make_float2(acc0, acc1);
        }
        __syncthreads();   // B1: xpart + h_lds (from prev Phase C) visible

        const float2 xa = xpart[0], xb = xpart[1];
        const float x0 = xa.x + xb.x;
        const float x1 = xa.y + xb.y;

        // Phase B: gates[t] = x@W_ih[t,:] + h . W_hh[t,:] + bias  (packed fp32 fma)
        vf4 acc4a = {0.f, 0.f, 0.f, 0.f}, acc4b = {0.f, 0.f, 0.f, 0.f};
        const vf4* h4 = reinterpret_cast<const vf4*>(h_lds);
        #pragma unroll
        for (int q = 0; q < 32; q += 2) {
            acc4a = __builtin_elementwise_fma(wr[q],     h4[q],     acc4a);  // ds_read_b128 broadcast
            acc4b = __builtin_elementwise_fma(wr[q + 1], h4[q + 1], acc4b);
        }
        const vf4 acc4 = acc4a + acc4b;
        float acc = (acc4.x + acc4.y) + (acc4.z + acc4.w);
        acc += fmaf(x0, wi0, fmaf(x1, wi1, bias));
        gbuf[t] = acc;
        __syncthreads();   // B2: gates ready

        // Phase C: LSTM pointwise update (threads 0..127 own c[d], h[d])
        if (t < ND) {
            const float gi = gbuf[t];
            const float gf = gbuf[ND + t];
            const float gg = gbuf[2 * ND + t];
            const float go = gbuf[3 * ND + t];
            const float si = __builtin_amdgcn_rcpf(1.0f + __builtin_amdgcn_exp2f(-L2E * gi));
            const float sf = __builtin_amdgcn_rcpf(1.0f + __builtin_amdgcn_exp2f(-L2E * gf));
            const float so = __builtin_amdgcn_rcpf(1.0f + __builtin_amdgcn_exp2f(-L2E * go));
            const float tg = 1.0f - 2.0f * __builtin_amdgcn_rcpf(__builtin_amdgcn_exp2f(2.0f * L2E * gg) + 1.0f);
            c_reg = sf * c_reg + si * tg;
            const float tc2 = 1.0f - 2.0f * __builtin_amdgcn_rcpf(__builtin_amdgcn_exp2f(2.0f * L2E * c_reg) + 1.0f);
            h_reg = so * tc2;
            h_lds[t] = h_reg;
            out[step * (NB * ND) + b * ND + t] = h_reg;   // [S,B,D]
        }
        // no barrier here: next step's B1 orders h_lds/gbuf/xpart hazards
    }
}

extern "C" void kernel_launch(void* const* d_in, const int* in_sizes, int n_in,
                              void* d_out, int out_size, void* d_ws, size_t ws_size,
                              hipStream_t stream) {
    const float* enc = (const float*)d_in[0];
    const float* W1w = (const float*)d_in[1];
    const float* W1b = (const float*)d_in[2];
    const float* W2w = (const float*)d_in[3];
    const float* W2b = (const float*)d_in[4];
    const float* Wih = (const float*)d_in[5];
    const float* Whh = (const float*)d_in[6];
    const float* bih = (const float*)d_in[7];
    const float* bhh = (const float*)d_in[8];
    attn_lstm_decoder<<<NB, NT, 0, stream>>>(enc, W1w, W1b, W2w, W2b,
                                             Wih, Whh, bih, bhh, (float*)d_out);
}

// Round 4
// 370.584 us; speedup vs baseline: 3.1537x; 1.0495x over previous
//
#include <hip/hip_runtime.h>

#define NB 256   // batch
#define NS 256   // seq len == number of steps
#define NE 2     // encoder dim
#define ND 128   // decoder dim
#define NT 512   // threads per block (8 waves)
#define NN 16    // Chebyshev nodes/degree for the h -> context map

typedef float vf4 __attribute__((ext_vector_type(4)));

constexpr float L2E = 1.4426950408889634f;  // log2(e)
constexpr float PI_F = 3.14159265358979323846f;

// One block per batch element; full 256-step recurrence inside the block.
// Attention is collapsed (setup-time) to a degree-15 Chebyshev polynomial
// G_e(h): x_e = sum_d G_e(h_d)/D. Per step:
//   gates[r] = W_hh[r,:].h + x0*wi0[r] + x1*wi1[r] + bias[r]
// Thread (g=t>>2, q=t&3) owns rows {g+128j} x K-slice [32q,32q+32): each
// thread reads only 128 B of h from LDS (4x less LDS return traffic than
// row-per-thread), gate reduction is 2 intra-group shuffles, Phase C is
// redundant on the 4 lanes so h stays in-register. One barrier per step.
__global__ __launch_bounds__(NT, 2)
void attn_lstm_decoder(const float* __restrict__ enc,   // [B,S,E]
                       const float* __restrict__ W1w,   // [S,S]
                       const float* __restrict__ W1b,   // [S]
                       const float* __restrict__ W2w,   // [S,2S]
                       const float* __restrict__ W2b,   // [S]
                       const float* __restrict__ Wih,   // [4D,E]
                       const float* __restrict__ Whh,   // [4D,D]
                       const float* __restrict__ bih,   // [4D]
                       const float* __restrict__ bhh,   // [4D]
                       float* __restrict__ out)         // [S,B,D]
{
    const int b    = blockIdx.x;
    const int t    = threadIdx.x;
    const int wave = t >> 6;
    const int lane = t & 63;
    const int g    = t >> 2;          // d-index / row group, 0..127
    const int q    = t & 3;           // K-slice quarter
    // setup-only:
    const int half = lane >> 5;
    const int idx  = lane & 31;
    const int jnode = 2 * wave + half;

    // h slices padded to 36 words so the 4 slice bases hit disjoint banks.
    __shared__ __align__(16) float hbuf[2][144];
    __shared__ __align__(16) float xwbuf[2][16];   // 8 waves x float2 partial x
    __shared__ float A2_l[NS];        // 2*log2e*(w2term + W2_b + W1_b)
    __shared__ float g2_l[NS];        // 2*log2e*w1sum
    __shared__ float e0_l[NS];        // enc[b,s,0]
    __shared__ float e1_l[NS];        // enc[b,s,1]
    __shared__ float Ml[NN * NN];     // DCT: c_i = sum_j M[i][j] F(y_j)
    __shared__ float2 Pn[NN];         // F(y_j) per node
    __shared__ float2 Vl[NN];         // Chebyshev coeffs of F, 1/ND folded in

    // ---------------- setup (once per block) ----------------
    {
        float v = enc[b * (NS * NE) + t];      // coalesced
        if (t & 1) e1_l[t >> 1] = v; else e0_l[t >> 1] = v;
    }
    if (t < NN * NN) {
        const int mi = t >> 4, mj = t & 15;
        const float w = (mi == 0) ? (1.0f / NN) : (2.0f / NN);
        Ml[t] = w * __cosf((float)(mi * (2 * mj + 1)) * (PI_F / (2 * NN)));
    }
    __syncthreads();

    // w1sum rows and w2term rows: 32 rows per wave, coalesced column reads.
    for (int r = 0; r < 32; ++r) {
        const int s = wave * 32 + r;
        float p = W1w[s * NS + lane]       + W1w[s * NS + lane + 64]
                + W1w[s * NS + lane + 128] + W1w[s * NS + lane + 192];
        #pragma unroll
        for (int m = 32; m >= 1; m >>= 1) p += __shfl_xor(p, m);
        if (lane == 0) g2_l[s] = p * (2.0f * L2E);
        float qq = 0.0f;
        #pragma unroll
        for (int kk = 0; kk < 8; ++kk) {
            const int c = lane + kk * 64;
            const float ev = (c & 1) ? e1_l[c >> 1] : e0_l[c >> 1];
            qq = fmaf(ev, W2w[s * (2 * NS) + c], qq);
        }
        #pragma unroll
        for (int m = 32; m >= 1; m >>= 1) qq += __shfl_xor(qq, m);
        if (lane == 0) A2_l[s] = (qq + W2b[s] + W1b[s]) * (2.0f * L2E);
    }
    __syncthreads();

    // One-time node softmax: F(y_j) for the 16 Chebyshev nodes.
    {
        const float y  = __cosf((float)(2 * jnode + 1) * (PI_F / (2 * NN)));
        const float C2 = -2.0f * L2E;
        float l = 0.0f, p0 = 0.0f, p1 = 0.0f;
        #pragma unroll
        for (int k = 0; k < 8; ++k) {
            const int s = k * 32 + idx;
            const float m1 = fmaf(y, g2_l[s], A2_l[s]);
            const float u  = __builtin_amdgcn_exp2f(m1);
            const float rc = __builtin_amdgcn_rcpf(u + 1.0f);
            const float e  = __builtin_amdgcn_exp2f(rc * C2);
            l += e;
            p0 = fmaf(e, e0_l[s], p0);
            p1 = fmaf(e, e1_l[s], p1);
        }
        #pragma unroll
        for (int m = 1; m <= 16; m <<= 1) {
            l  += __shfl_xor(l, m);
            p0 += __shfl_xor(p0, m);
            p1 += __shfl_xor(p1, m);
        }
        if (idx == 0) {
            const float rl = __builtin_amdgcn_rcpf(l);
            Pn[jnode] = make_float2(p0 * rl, p1 * rl);
        }
    }
    __syncthreads();

    // DCT collapse: V[i] = sum_j M[i][j] * Pn[j], with 1/ND folded in.
    if (t < NN) {
        float v0 = 0.0f, v1 = 0.0f;
        #pragma unroll
        for (int j = 0; j < NN; ++j) {
            v0 = fmaf(Ml[t * NN + j], Pn[j].x, v0);
            v1 = fmaf(Ml[t * NN + j], Pn[j].y, v1);
        }
        Vl[t] = make_float2(v0 * (1.0f / ND), v1 * (1.0f / ND));
    }

    // W_hh slices for rows g+128j, K range [32q, 32q+32) -> 32 vf4 regs.
    vf4 wr[4][8];
    float wi0_[4], wi1_[4], bb_[4];
    #pragma unroll
    for (int j = 0; j < 4; ++j) {
        const int r = g + 128 * j;
        const vf4* W4 = reinterpret_cast<const vf4*>(Whh + r * ND + q * 32);
        #pragma unroll
        for (int i = 0; i < 8; ++i) wr[j][i] = W4[i];
        wi0_[j] = Wih[r * 2 + 0];
        wi1_[j] = Wih[r * 2 + 1];
        bb_[j]  = bih[r] + bhh[r];
    }

    if (t < ND) hbuf[0][36 * (t >> 5) + (t & 31)] = 0.0f;
    float h_reg = 0.0f, c_reg = 0.0f;
    __syncthreads();

    float V0r[NN], V1r[NN];
    #pragma unroll
    for (int i = 0; i < NN; ++i) { V0r[i] = Vl[i].x; V1r[i] = Vl[i].y; }

    // Phase G helper: poly on own h (redundant x4 in group), wave reduce over
    // groups only (skip xor 1,2 — group lanes identical), lane0 -> xwbuf[pw].
    auto phaseG = [&](float h, int pw) {
        float acc0 = fmaf(V0r[1], h, V0r[0]);
        float acc1 = fmaf(V1r[1], h, V1r[0]);
        float tp = 1.0f, tc = h;
        const float h2 = h + h;
        #pragma unroll
        for (int i = 2; i < NN; ++i) {
            const float tn = fmaf(h2, tc, -tp);
            acc0 = fmaf(V0r[i], tn, acc0);
            acc1 = fmaf(V1r[i], tn, acc1);
            tp = tc; tc = tn;
        }
        #pragma unroll
        for (int m = 4; m <= 32; m <<= 1) {     // sum one copy per group
            acc0 += __shfl_xor(acc0, m);
            acc1 += __shfl_xor(acc1, m);
        }
        if (lane == 0) {
            xwbuf[pw][2 * wave + 0] = acc0;
            xwbuf[pw][2 * wave + 1] = acc1;
        }
    };

    phaseG(0.0f, 0);       // x for step 0 (h = 0)
    __syncthreads();

    // ---------------- the recurrence (ONE barrier per step) ----------------
    for (int step = 0; step < NS; ++step) {
        const int pr = step & 1;
        const int pw = pr ^ 1;

        // Partial gate dots over this thread's 32-element h slice.
        const vf4* hb = reinterpret_cast<const vf4*>(&hbuf[pr][0]) + 9 * q;
        vf4 a0 = {0.f,0.f,0.f,0.f}, a1 = a0, a2 = a0, a3 = a0;
        #pragma unroll
        for (int i = 0; i < 8; ++i) {
            const vf4 hv = hb[i];                     // 16-way bcast, no conflict
            a0 = __builtin_elementwise_fma(wr[0][i], hv, a0);
            a1 = __builtin_elementwise_fma(wr[1][i], hv, a1);
            a2 = __builtin_elementwise_fma(wr[2][i], hv, a2);
            a3 = __builtin_elementwise_fma(wr[3][i], hv, a3);
        }
        float d0 = (a0.x + a0.y) + (a0.z + a0.w);
        float d1 = (a1.x + a1.y) + (a1.z + a1.w);
        float d2 = (a2.x + a2.y) + (a2.z + a2.w);
        float d3 = (a3.x + a3.y) + (a3.z + a3.w);
        // sum the 4 K-slices (group lanes are consecutive in the wave)
        d0 += __shfl_xor(d0, 1);  d0 += __shfl_xor(d0, 2);
        d1 += __shfl_xor(d1, 1);  d1 += __shfl_xor(d1, 2);
        d2 += __shfl_xor(d2, 1);  d2 += __shfl_xor(d2, 2);
        d3 += __shfl_xor(d3, 1);  d3 += __shfl_xor(d3, 2);

        // x = sum of 8 per-wave float2 partials: lane-parallel gather+butterfly
        float2 xv = *reinterpret_cast<const float2*>(&xwbuf[pr][2 * (lane & 7)]);
        xv.x += __shfl_xor(xv.x, 1);  xv.y += __shfl_xor(xv.y, 1);
        xv.x += __shfl_xor(xv.x, 2);  xv.y += __shfl_xor(xv.y, 2);
        xv.x += __shfl_xor(xv.x, 4);  xv.y += __shfl_xor(xv.y, 4);

        const float gi = d0 + fmaf(xv.x, wi0_[0], fmaf(xv.y, wi1_[0], bb_[0]));
        const float gf = d1 + fmaf(xv.x, wi0_[1], fmaf(xv.y, wi1_[1], bb_[1]));
        const float gg = d2 + fmaf(xv.x, wi0_[2], fmaf(xv.y, wi1_[2], bb_[2]));
        const float go = d3 + fmaf(xv.x, wi0_[3], fmaf(xv.y, wi1_[3], bb_[3]));

        // LSTM pointwise (redundant on the 4 group lanes -> h stays in-register)
        const float si = __builtin_amdgcn_rcpf(1.0f + __builtin_amdgcn_exp2f(-L2E * gi));
        const float sf = __builtin_amdgcn_rcpf(1.0f + __builtin_amdgcn_exp2f(-L2E * gf));
        const float so = __builtin_amdgcn_rcpf(1.0f + __builtin_amdgcn_exp2f(-L2E * go));
        const float tg = 1.0f - 2.0f * __builtin_amdgcn_rcpf(__builtin_amdgcn_exp2f(2.0f * L2E * gg) + 1.0f);
        c_reg = sf * c_reg + si * tg;
        const float tc2 = 1.0f - 2.0f * __builtin_amdgcn_rcpf(__builtin_amdgcn_exp2f(2.0f * L2E * c_reg) + 1.0f);
        h_reg = so * tc2;

        if (q == 0) {
            hbuf[pw][36 * (g >> 5) + (g & 31)] = h_reg;      // consumed post-barrier
            out[step * (NB * ND) + b * ND + g] = h_reg;      // [S,B,D]
        }
        phaseG(h_reg, pw);                                   // x for step k+1

        __syncthreads();
    }
}

extern "C" void kernel_launch(void* const* d_in, const int* in_sizes, int n_in,
                              void* d_out, int out_size, void* d_ws, size_t ws_size,
                              hipStream_t stream) {
    const float* enc = (const float*)d_in[0];
    const float* W1w = (const float*)d_in[1];
    const float* W1b = (const float*)d_in[2];
    const float* W2w = (const float*)d_in[3];
    const float* W2b = (const float*)d_in[4];
    const float* Wih = (const float*)d_in[5];
    const float* Whh = (const float*)d_in[6];
    const float* bih = (const float*)d_in[7];
    const float* bhh = (const float*)d_in[8];
    attn_lstm_decoder<<<NB, NT, 0, stream>>>(enc, W1w, W1b, W2w, W2b,
                                             Wih, Whh, bih, bhh, (float*)d_out);
}

// Round 6
// 318.068 us; speedup vs baseline: 3.6745x; 1.1651x over previous
//
#include <hip/hip_runtime.h>

#define NB 256   // batch
#define NS 256   // seq len == number of steps
#define NE 2     // encoder dim
#define ND 128   // decoder dim
#define NT 512   // threads per block (8 waves)
#define NN 16    // Chebyshev nodes/degree for the h -> context map
#define RING 32  // h-history ring depth (2 store chunks of 16)
#define SLOT 144 // padded words per ring slot (4 slices of 36)

typedef float vf4 __attribute__((ext_vector_type(4)));

constexpr float L2E = 1.4426950408889634f;  // log2(e)
constexpr float PI_F = 3.14159265358979323846f;

// DPP add: x + dpp_move(x). All-VALU cross-lane (no LDS pipe, no lgkmcnt).
template <int C>
__device__ __forceinline__ float dppadd(float x) {
    return x + __builtin_bit_cast(float,
        __builtin_amdgcn_update_dpp(0, __builtin_bit_cast(int, x), C, 0xF, 0xF, true));
}
// quad_perm(1,0,3,2)=0xB1 (xor1), quad_perm(2,3,0,1)=0x4E (xor2),
// row_half_mirror=0x141, row_mirror=0x140, row_bcast15=0x142, row_bcast31=0x143.
__device__ __forceinline__ float red_quad(float x) {      // sum over each quad, valid all lanes
    x = dppadd<0xB1>(x); x = dppadd<0x4E>(x); return x;
}
__device__ __forceinline__ float red_oct(float x) {       // sum over each octet, valid all lanes
    x = dppadd<0xB1>(x); x = dppadd<0x4E>(x); x = dppadd<0x141>(x); return x;
}
__device__ __forceinline__ float red_wave64(float x) {    // valid in lane 63
    x = dppadd<0xB1>(x); x = dppadd<0x4E>(x); x = dppadd<0x141>(x);
    x = dppadd<0x140>(x); x = dppadd<0x142>(x); x = dppadd<0x143>(x); return x;
}
__device__ __forceinline__ float red_half32(float x) {    // 32-lane sums, valid lanes 31 & 63
    x = dppadd<0xB1>(x); x = dppadd<0x4E>(x); x = dppadd<0x141>(x);
    x = dppadd<0x140>(x); x = dppadd<0x142>(x); return x;
}
__device__ __forceinline__ float red_grp16(float x) {     // quads hold identical copies;
    // mirrors/bcasts add ONE copy per quad => returns EXACT sum over the 16
    // distinct quad values (NO x4 overcount!), valid in lane 63.
    x = dppadd<0x141>(x); x = dppadd<0x140>(x);
    x = dppadd<0x142>(x); x = dppadd<0x143>(x); return x;
}

// One block per batch element; 256-step recurrence in-block, ONE barrier/step.
// Attention collapsed to degree-15 Chebyshev poly G_e(h) (setup); per step
// x_e = sum_d G_e(h_d)/D. Gate dots: thread(g=t>>2,q=t&3) owns rows {g+128j} x
// K-quarter q; quad-DPP reduce. h history in a 32-slot LDS ring; chunk-stored
// to global every 16 steps at step TOP so the store ack never blocks a barrier.
__global__ __launch_bounds__(NT, 2)
void attn_lstm_decoder(const float* __restrict__ enc,   // [B,S,E]
                       const float* __restrict__ W1w,   // [S,S]
                       const float* __restrict__ W1b,   // [S]
                       const float* __restrict__ W2w,   // [S,2S]
                       const float* __restrict__ W2b,   // [S]
                       const float* __restrict__ Wih,   // [4D,E]
                       const float* __restrict__ Whh,   // [4D,D]
                       const float* __restrict__ bih,   // [4D]
                       const float* __restrict__ bhh,   // [4D]
                       float* __restrict__ out)         // [S,B,D]
{
    const int b    = blockIdx.x;
    const int t    = threadIdx.x;
    const int wave = t >> 6;
    const int lane = t & 63;
    const int g    = t >> 2;          // d-index / row group, 0..127
    const int q    = t & 3;           // K-slice quarter
    // setup-only:
    const int half = lane >> 5;
    const int idx  = lane & 31;
    const int jnode = 2 * wave + half;

    __shared__ __align__(16) float hist[RING * SLOT];   // h ring: slot s&31, 4 slices of 36
    __shared__ __align__(16) float xwbuf[2][16];        // 8 waves x float2 partial x
    __shared__ float A2_l[NS];        // 2*log2e*(w2term + W2_b + W1_b)
    __shared__ float g2_l[NS];        // 2*log2e*w1sum
    __shared__ float e0_l[NS];        // enc[b,s,0]
    __shared__ float e1_l[NS];        // enc[b,s,1]
    __shared__ float Ml[NN * NN];     // DCT: c_i = sum_j M[i][j] F(y_j)
    __shared__ float2 Pn[NN];         // F(y_j) per node
    __shared__ float2 Vl[NN];         // Chebyshev coeffs, 1/ND folded in

    // ---------------- setup (once per block) ----------------
    {
        float v = enc[b * (NS * NE) + t];      // coalesced
        if (t & 1) e1_l[t >> 1] = v; else e0_l[t >> 1] = v;
    }
    if (t < NN * NN) {
        const int mi = t >> 4, mj = t & 15;
        const float w = (mi == 0) ? (1.0f / NN) : (2.0f / NN);
        Ml[t] = w * __cosf((float)(mi * (2 * mj + 1)) * (PI_F / (2 * NN)));
    }
    __syncthreads();

    // w1sum rows and w2term rows: 32 rows per wave (DPP reductions).
    for (int r = 0; r < 32; ++r) {
        const int s = wave * 32 + r;
        float p = W1w[s * NS + lane]       + W1w[s * NS + lane + 64]
                + W1w[s * NS + lane + 128] + W1w[s * NS + lane + 192];
        p = red_wave64(p);
        if (lane == 63) g2_l[s] = p * (2.0f * L2E);
        float qq = 0.0f;
        #pragma unroll
        for (int kk = 0; kk < 8; ++kk) {
            const int c = lane + kk * 64;
            const float ev = (c & 1) ? e1_l[c >> 1] : e0_l[c >> 1];
            qq = fmaf(ev, W2w[s * (2 * NS) + c], qq);
        }
        qq = red_wave64(qq);
        if (lane == 63) A2_l[s] = (qq + W2b[s] + W1b[s]) * (2.0f * L2E);
    }
    __syncthreads();

    // One-time node softmax: F(y_j) for the 16 Chebyshev nodes (2 nodes/wave).
    {
        const float y  = __cosf((float)(2 * jnode + 1) * (PI_F / (2 * NN)));
        const float C2 = -2.0f * L2E;
        float l = 0.0f, p0 = 0.0f, p1 = 0.0f;
        #pragma unroll
        for (int k = 0; k < 8; ++k) {
            const int s = k * 32 + idx;
            const float m1 = fmaf(y, g2_l[s], A2_l[s]);
            const float u  = __builtin_amdgcn_exp2f(m1);
            const float rc = __builtin_amdgcn_rcpf(u + 1.0f);
            const float e  = __builtin_amdgcn_exp2f(rc * C2);
            l += e;
            p0 = fmaf(e, e0_l[s], p0);
            p1 = fmaf(e, e1_l[s], p1);
        }
        l = red_half32(l); p0 = red_half32(p0); p1 = red_half32(p1);
        if ((lane & 31) == 31) {
            const float rl = __builtin_amdgcn_rcpf(l);
            Pn[jnode] = make_float2(p0 * rl, p1 * rl);
        }
    }
    __syncthreads();

    // DCT collapse: V[i] = sum_j M[i][j]*Pn[j], with ONLY 1/ND folded in
    // (red_grp16 is an exact group-sum; R5's 1/4 "duplication" fold was the bug).
    if (t < NN) {
        float v0 = 0.0f, v1 = 0.0f;
        #pragma unroll
        for (int j = 0; j < NN; ++j) {
            v0 = fmaf(Ml[t * NN + j], Pn[j].x, v0);
            v1 = fmaf(Ml[t * NN + j], Pn[j].y, v1);
        }
        Vl[t] = make_float2(v0 * (1.0f / ND), v1 * (1.0f / ND));
    }

    // W_hh slices for rows g+128j, K range [32q, 32q+32) -> 32 vf4 regs.
    vf4 wr[4][8];
    float wi0_[4], wi1_[4], bb_[4];
    #pragma unroll
    for (int j = 0; j < 4; ++j) {
        const int r = g + 128 * j;
        const vf4* W4 = reinterpret_cast<const vf4*>(Whh + r * ND + q * 32);
        #pragma unroll
        for (int i = 0; i < 8; ++i) wr[j][i] = W4[i];
        wi0_[j] = Wih[r * 2 + 0];
        wi1_[j] = Wih[r * 2 + 1];
        bb_[j]  = bih[r] + bhh[r];
    }

    // zero-init ring slot 31 (input of step 0)
    if (t < ND) hist[31 * SLOT + 36 * (t >> 5) + (t & 31)] = 0.0f;
    float h_reg = 0.0f, c_reg = 0.0f;
    __syncthreads();

    float V0r[NN], V1r[NN];
    #pragma unroll
    for (int i = 0; i < NN; ++i) { V0r[i] = Vl[i].x; V1r[i] = Vl[i].y; }

    // phaseG: Chebyshev poly on own h (x4 quad redundancy), DPP wave-reduce,
    // lane63 writes this wave's float2 partial.
    auto phaseG = [&](float h, int pw) {
        float acc0 = fmaf(V0r[1], h, V0r[0]);
        float acc1 = fmaf(V1r[1], h, V1r[0]);
        float tp = 1.0f, tc = h;
        const float h2 = h + h;
        #pragma unroll
        for (int i = 2; i < NN; ++i) {
            const float tn = fmaf(h2, tc, -tp);
            acc0 = fmaf(V0r[i], tn, acc0);
            acc1 = fmaf(V1r[i], tn, acc1);
            tp = tc; tc = tn;
        }
        acc0 = red_grp16(acc0);
        acc1 = red_grp16(acc1);
        if (lane == 63) {
            xwbuf[pw][2 * wave + 0] = acc0;
            xwbuf[pw][2 * wave + 1] = acc1;
        }
    };

    phaseG(0.0f, 0);       // x for step 0 (h = 0)
    __syncthreads();

    // ---------------- the recurrence (ONE barrier per step) ----------------
    for (int step = 0; step < NS; ++step) {
        const int pr = step & 1;
        const int rs = (step + RING - 1) & (RING - 1);   // slot holding h(step-1)
        const int ws = step & (RING - 1);                // slot for h(step)

        // Chunk store (every 16 steps, at step TOP): steps step-16..step-1.
        // Ack retires under this step's compute; the other ring half is being
        // written this chunk, so no read/write race.
        if ((step & 15) == 0 && step > 0) {
            const int sb  = (step - 16) & (RING - 1);
            const int k   = t >> 5;            // which of the 16 steps
            const int l32 = t & 31;            // 128 floats / 32 lanes, vf4 each
            const int w   = 4 * l32;
            const vf4 v = *reinterpret_cast<const vf4*>(
                &hist[(sb + k) * SLOT + 36 * (w >> 5) + (w & 31)]);
            *reinterpret_cast<vf4*>(
                &out[(size_t)(step - 16 + k) * (NB * ND) + b * ND + w]) = v;
        }

        // x = sum of 8 per-wave float2 partials: 1 ds_read_b64 + octet DPP.
        float2 xv = *reinterpret_cast<const float2*>(&xwbuf[pr][2 * (lane & 7)]);
        float x0 = red_oct(xv.x);
        float x1 = red_oct(xv.y);

        // Gate dots over this thread's 32-element h slice (16-way broadcast).
        const vf4* hb = reinterpret_cast<const vf4*>(&hist[rs * SLOT]) + 9 * q;
        vf4 a0 = {0.f,0.f,0.f,0.f}, a1 = a0, a2 = a0, a3 = a0;
        #pragma unroll
        for (int i = 0; i < 8; ++i) {
            const vf4 hv = hb[i];
            a0 = __builtin_elementwise_fma(wr[0][i], hv, a0);
            a1 = __builtin_elementwise_fma(wr[1][i], hv, a1);
            a2 = __builtin_elementwise_fma(wr[2][i], hv, a2);
            a3 = __builtin_elementwise_fma(wr[3][i], hv, a3);
        }
        float d0 = (a0.x + a0.y) + (a0.z + a0.w);
        float d1 = (a1.x + a1.y) + (a1.z + a1.w);
        float d2 = (a2.x + a2.y) + (a2.z + a2.w);
        float d3 = (a3.x + a3.y) + (a3.z + a3.w);
        d0 = red_quad(d0);  d1 = red_quad(d1);            // sum the 4 K-slices
        d2 = red_quad(d2);  d3 = red_quad(d3);

        const float gi = d0 + fmaf(x0, wi0_[0], fmaf(x1, wi1_[0], bb_[0]));
        const float gf = d1 + fmaf(x0, wi0_[1], fmaf(x1, wi1_[1], bb_[1]));
        const float gg = d2 + fmaf(x0, wi0_[2], fmaf(x1, wi1_[2], bb_[2]));
        const float go = d3 + fmaf(x0, wi0_[3], fmaf(x1, wi1_[3], bb_[3]));

        // LSTM pointwise (redundant on the 4 group lanes -> h stays in-register)
        const float si = __builtin_amdgcn_rcpf(1.0f + __builtin_amdgcn_exp2f(-L2E * gi));
        const float sf = __builtin_amdgcn_rcpf(1.0f + __builtin_amdgcn_exp2f(-L2E * gf));
        const float so = __builtin_amdgcn_rcpf(1.0f + __builtin_amdgcn_exp2f(-L2E * go));
        const float tg = 1.0f - 2.0f * __builtin_amdgcn_rcpf(__builtin_amdgcn_exp2f(2.0f * L2E * gg) + 1.0f);
        c_reg = sf * c_reg + si * tg;
        const float tc2 = 1.0f - 2.0f * __builtin_amdgcn_rcpf(__builtin_amdgcn_exp2f(2.0f * L2E * c_reg) + 1.0f);
        h_reg = so * tc2;

        if (q == 0) hist[ws * SLOT + 36 * (g >> 5) + (g & 31)] = h_reg;
        phaseG(h_reg, pr ^ 1);                            // x for step k+1

        __syncthreads();
    }

    // Tail: store the final chunk (steps 240..255, ring slots 16..31).
    {
        const int k   = t >> 5;
        const int l32 = t & 31;
        const int w   = 4 * l32;
        const vf4 v = *reinterpret_cast<const vf4*>(
            &hist[(16 + k) * SLOT + 36 * (w >> 5) + (w & 31)]);
        *reinterpret_cast<vf4*>(
            &out[(size_t)(240 + k) * (NB * ND) + b * ND + w]) = v;
    }
}

extern "C" void kernel_launch(void* const* d_in, const int* in_sizes, int n_in,
                              void* d_out, int out_size, void* d_ws, size_t ws_size,
                              hipStream_t stream) {
    const float* enc = (const float*)d_in[0];
    const float* W1w = (const float*)d_in[1];
    const float* W1b = (const float*)d_in[2];
    const float* W2w = (const float*)d_in[3];
    const float* W2b = (const float*)d_in[4];
    const float* Wih = (const float*)d_in[5];
    const float* Whh = (const float*)d_in[6];
    const float* bih = (const float*)d_in[7];
    const float* bhh = (const float*)d_in[8];
    attn_lstm_decoder<<<NB, NT, 0, stream>>>(enc, W1w, W1b, W2w, W2b,
                                             Wih, Whh, bih, bhh, (float*)d_out);
}

// Round 7
// 308.588 us; speedup vs baseline: 3.7873x; 1.0307x over previous
//
#include <hip/hip_runtime.h>

#define NB 256   // batch
#define NS 256   // seq len == number of steps
#define NE 2     // encoder dim
#define ND 128   // decoder dim
#define NT 512   // threads per block (8 waves)
#define NN 16    // Chebyshev nodes/degree for the h -> context map
#define RING 32  // h-history ring depth (2 store chunks of 16)
#define SLOT 144 // padded words per ring slot (4 slices of 36)

typedef float vf4 __attribute__((ext_vector_type(4)));

constexpr float L2E = 1.4426950408889634f;  // log2(e)
constexpr float PI_F = 3.14159265358979323846f;

// Monomial coefficients of Chebyshev T_k: T_k(h) = sum_m CT[k][m] h^m (exact ints).
__device__ const float CT[16][16] = {
 {1,0,0,0,0,0,0,0,0,0,0,0,0,0,0,0},
 {0,1,0,0,0,0,0,0,0,0,0,0,0,0,0,0},
 {-1,0,2,0,0,0,0,0,0,0,0,0,0,0,0,0},
 {0,-3,0,4,0,0,0,0,0,0,0,0,0,0,0,0},
 {1,0,-8,0,8,0,0,0,0,0,0,0,0,0,0,0},
 {0,5,0,-20,0,16,0,0,0,0,0,0,0,0,0,0},
 {-1,0,18,0,-48,0,32,0,0,0,0,0,0,0,0,0},
 {0,-7,0,56,0,-112,0,64,0,0,0,0,0,0,0,0},
 {1,0,-32,0,160,0,-256,0,128,0,0,0,0,0,0,0},
 {0,9,0,-120,0,432,0,-576,0,256,0,0,0,0,0,0},
 {-1,0,50,0,-400,0,1120,0,-1280,0,512,0,0,0,0,0},
 {0,-11,0,220,0,-1232,0,2816,0,-2816,0,1024,0,0,0,0},
 {1,0,-72,0,840,0,-3584,0,6912,0,-6144,0,2048,0,0,0},
 {0,13,0,-364,0,2912,0,-9984,0,16640,0,-13312,0,4096,0,0},
 {-1,0,98,0,-1568,0,9408,0,-26880,0,39424,0,-28672,0,8192,0},
 {0,-15,0,560,0,-6048,0,28800,0,-70400,0,92160,0,-61440,0,16384}};

// DPP add: x + dpp_move(x). All-VALU cross-lane (no LDS pipe, no lgkmcnt).
template <int C>
__device__ __forceinline__ float dppadd(float x) {
    return x + __builtin_bit_cast(float,
        __builtin_amdgcn_update_dpp(0, __builtin_bit_cast(int, x), C, 0xF, 0xF, true));
}
// quad_perm(1,0,3,2)=0xB1 (xor1), quad_perm(2,3,0,1)=0x4E (xor2),
// row_half_mirror=0x141, row_mirror=0x140, row_bcast15=0x142, row_bcast31=0x143.
__device__ __forceinline__ float red_quad(float x) {      // sum over each quad, valid all lanes
    x = dppadd<0xB1>(x); x = dppadd<0x4E>(x); return x;
}
__device__ __forceinline__ float red_oct(float x) {       // sum over each octet, valid all lanes
    x = dppadd<0xB1>(x); x = dppadd<0x4E>(x); x = dppadd<0x141>(x); return x;
}
__device__ __forceinline__ float red_wave64(float x) {    // valid in lane 63
    x = dppadd<0xB1>(x); x = dppadd<0x4E>(x); x = dppadd<0x141>(x);
    x = dppadd<0x140>(x); x = dppadd<0x142>(x); x = dppadd<0x143>(x); return x;
}
__device__ __forceinline__ float red_half32(float x) {    // 32-lane sums, valid lanes 31 & 63
    x = dppadd<0xB1>(x); x = dppadd<0x4E>(x); x = dppadd<0x141>(x);
    x = dppadd<0x140>(x); x = dppadd<0x142>(x); return x;
}
__device__ __forceinline__ float red_grp16(float x) {     // quads hold identical copies;
    // mirrors/bcasts add ONE copy per quad => EXACT sum over 16 quad values.
    x = dppadd<0x141>(x); x = dppadd<0x140>(x);
    x = dppadd<0x142>(x); x = dppadd<0x143>(x); return x;
}

// One block per batch element; 256-step recurrence in-block, ONE barrier/step.
// Attention collapsed (setup) to a degree-15 polynomial G_e(h) in MONOMIAL
// form, split across the quad: lane q evaluates h^q * Q_q(h^4); red_quad
// reassembles. Gate dots: thread(g,q) owns rows {g+128j} x K-quarter q.
// h history in a 32-slot LDS ring; chunk-stored every 16 steps at step TOP.
__global__ __launch_bounds__(NT, 2)
void attn_lstm_decoder(const float* __restrict__ enc,   // [B,S,E]
                       const float* __restrict__ W1w,   // [S,S]
                       const float* __restrict__ W1b,   // [S]
                       const float* __restrict__ W2w,   // [S,2S]
                       const float* __restrict__ W2b,   // [S]
                       const float* __restrict__ Wih,   // [4D,E]
                       const float* __restrict__ Whh,   // [4D,D]
                       const float* __restrict__ bih,   // [4D]
                       const float* __restrict__ bhh,   // [4D]
                       float* __restrict__ out)         // [S,B,D]
{
    const int b    = blockIdx.x;
    const int t    = threadIdx.x;
    const int wave = t >> 6;
    const int lane = t & 63;
    const int g    = t >> 2;          // d-index / row group, 0..127
    const int q    = t & 3;           // K-slice quarter / monomial residue
    const bool qb0 = q & 1;
    const bool qb1 = q & 2;
    // setup-only:
    const int half = lane >> 5;
    const int idx  = lane & 31;
    const int jnode = 2 * wave + half;

    __shared__ __align__(16) float hist[RING * SLOT];   // h ring
    __shared__ __align__(16) float xwbuf[2][16];        // 8 waves x float2 partial x
    __shared__ float A2_l[NS];        // 2*log2e*(w2term + W2_b + W1_b)
    __shared__ float g2_l[NS];        // 2*log2e*w1sum
    __shared__ float e0_l[NS];        // enc[b,s,0]
    __shared__ float e1_l[NS];        // enc[b,s,1]
    __shared__ float Ml[NN * NN];     // DCT: c_i = sum_j M[i][j] F(y_j)
    __shared__ float2 Pn[NN];         // F(y_j) per node
    __shared__ float2 Vl[NN];         // Chebyshev coeffs, 1/ND folded in
    __shared__ float Pm0[NN], Pm1[NN];// monomial coeffs of G

    // ---------------- setup (once per block) ----------------
    {
        float v = enc[b * (NS * NE) + t];      // coalesced
        if (t & 1) e1_l[t >> 1] = v; else e0_l[t >> 1] = v;
    }
    if (t < NN * NN) {
        const int mi = t >> 4, mj = t & 15;
        const float w = (mi == 0) ? (1.0f / NN) : (2.0f / NN);
        Ml[t] = w * __cosf((float)(mi * (2 * mj + 1)) * (PI_F / (2 * NN)));
    }
    __syncthreads();

    // w1sum rows and w2term rows: 32 rows per wave (DPP reductions).
    for (int r = 0; r < 32; ++r) {
        const int s = wave * 32 + r;
        float p = W1w[s * NS + lane]       + W1w[s * NS + lane + 64]
                + W1w[s * NS + lane + 128] + W1w[s * NS + lane + 192];
        p = red_wave64(p);
        if (lane == 63) g2_l[s] = p * (2.0f * L2E);
        float qq = 0.0f;
        #pragma unroll
        for (int kk = 0; kk < 8; ++kk) {
            const int c = lane + kk * 64;
            const float ev = (c & 1) ? e1_l[c >> 1] : e0_l[c >> 1];
            qq = fmaf(ev, W2w[s * (2 * NS) + c], qq);
        }
        qq = red_wave64(qq);
        if (lane == 63) A2_l[s] = (qq + W2b[s] + W1b[s]) * (2.0f * L2E);
    }
    __syncthreads();

    // One-time node softmax: F(y_j) for the 16 Chebyshev nodes (2 nodes/wave).
    {
        const float y  = __cosf((float)(2 * jnode + 1) * (PI_F / (2 * NN)));
        const float C2 = -2.0f * L2E;
        float l = 0.0f, p0 = 0.0f, p1 = 0.0f;
        #pragma unroll
        for (int k = 0; k < 8; ++k) {
            const int s = k * 32 + idx;
            const float m1 = fmaf(y, g2_l[s], A2_l[s]);
            const float u  = __builtin_amdgcn_exp2f(m1);
            const float rc = __builtin_amdgcn_rcpf(u + 1.0f);
            const float e  = __builtin_amdgcn_exp2f(rc * C2);
            l += e;
            p0 = fmaf(e, e0_l[s], p0);
            p1 = fmaf(e, e1_l[s], p1);
        }
        l = red_half32(l); p0 = red_half32(p0); p1 = red_half32(p1);
        if ((lane & 31) == 31) {
            const float rl = __builtin_amdgcn_rcpf(l);
            Pn[jnode] = make_float2(p0 * rl, p1 * rl);
        }
    }
    __syncthreads();

    // DCT collapse: V[i] = sum_j M[i][j]*Pn[j], 1/ND folded in.
    if (t < NN) {
        float v0 = 0.0f, v1 = 0.0f;
        #pragma unroll
        for (int j = 0; j < NN; ++j) {
            v0 = fmaf(Ml[t * NN + j], Pn[j].x, v0);
            v1 = fmaf(Ml[t * NN + j], Pn[j].y, v1);
        }
        Vl[t] = make_float2(v0 * (1.0f / ND), v1 * (1.0f / ND));
    }

    // W_hh slices for rows g+128j, K range [32q, 32q+32) -> 32 vf4 regs.
    vf4 wr[4][8];
    float wi0_[4], wi1_[4], bb_[4];
    #pragma unroll
    for (int j = 0; j < 4; ++j) {
        const int r = g + 128 * j;
        const vf4* W4 = reinterpret_cast<const vf4*>(Whh + r * ND + q * 32);
        #pragma unroll
        for (int i = 0; i < 8; ++i) wr[j][i] = W4[i];
        wi0_[j] = Wih[r * 2 + 0];
        wi1_[j] = Wih[r * 2 + 1];
        bb_[j]  = bih[r] + bhh[r];
    }

    // zero-init ring slot 31 (input of step 0)
    if (t < ND) hist[31 * SLOT + 36 * (t >> 5) + (t & 31)] = 0.0f;
    float h_reg = 0.0f, c_reg = 0.0f;
    __syncthreads();                   // Vl visible

    // Chebyshev -> monomial: Pm[m] = sum_k V[k] * CT[k][m].
    if (t < NN) {
        float s0 = 0.0f, s1 = 0.0f;
        #pragma unroll
        for (int k = 0; k < NN; ++k) {
            s0 = fmaf(Vl[k].x, CT[k][t], s0);
            s1 = fmaf(Vl[k].y, CT[k][t], s1);
        }
        Pm0[t] = s0; Pm1[t] = s1;
    }
    __syncthreads();                   // Pm visible

    // Per-lane residue-class coefficients: G_e(h) = sum_q h^q * Q_q(h^4).
    float Q0[4], Q1[4];
    #pragma unroll
    for (int i = 0; i < 4; ++i) { Q0[i] = Pm0[4 * i + q]; Q1[i] = Pm1[4 * i + q]; }

    // phaseG: quad-split monomial eval; red_quad reassembles G(h), then
    // mirror-reduce over the 16 quads. lane63 writes this wave's partial.
    auto phaseG = [&](float h, int pw) {
        const float h2 = h * h;
        const float h3 = h2 * h;
        const float h4 = h2 * h2;
        const float hq = qb1 ? (qb0 ? h3 : h2) : (qb0 ? h : 1.0f);
        float a0 = fmaf(Q0[3], h4, Q0[2]);
        a0 = fmaf(a0, h4, Q0[1]);
        a0 = fmaf(a0, h4, Q0[0]);
        float a1 = fmaf(Q1[3], h4, Q1[2]);
        a1 = fmaf(a1, h4, Q1[1]);
        a1 = fmaf(a1, h4, Q1[0]);
        a0 *= hq;
        a1 *= hq;
        a0 = red_quad(a0);  a1 = red_quad(a1);     // reassemble G(h_g)
        a0 = red_grp16(a0); a1 = red_grp16(a1);    // sum over the wave's 16 g
        if (lane == 63) {
            xwbuf[pw][2 * wave + 0] = a0;
            xwbuf[pw][2 * wave + 1] = a1;
        }
    };

    phaseG(0.0f, 0);       // x for step 0 (h = 0)
    __syncthreads();

    // ---------------- the recurrence (ONE barrier per step) ----------------
    for (int step = 0; step < NS; ++step) {
        const int pr = step & 1;
        const int rs = (step + RING - 1) & (RING - 1);   // slot holding h(step-1)
        const int ws = step & (RING - 1);                // slot for h(step)

        // Front-load all LDS reads so their latency overlaps the chunk store.
        float2 xv = *reinterpret_cast<const float2*>(&xwbuf[pr][2 * (lane & 7)]);
        const vf4* hb = reinterpret_cast<const vf4*>(&hist[rs * SLOT]) + 9 * q;
        vf4 hv[8];
        #pragma unroll
        for (int i = 0; i < 8; ++i) hv[i] = hb[i];       // 16-way bcast b128

        // Chunk store (every 16 steps, at step TOP): steps step-16..step-1.
        if ((step & 15) == 0 && step > 0) {
            const int sb  = (step - 16) & (RING - 1);
            const int k   = t >> 5;
            const int l32 = t & 31;
            const int w   = 4 * l32;
            const vf4 v = *reinterpret_cast<const vf4*>(
                &hist[(sb + k) * SLOT + 36 * (w >> 5) + (w & 31)]);
            *reinterpret_cast<vf4*>(
                &out[(size_t)(step - 16 + k) * (NB * ND) + b * ND + w]) = v;
        }

        float x0 = red_oct(xv.x);
        float x1 = red_oct(xv.y);

        // Gate dots over this thread's 32-element h slice.
        vf4 a0 = {0.f,0.f,0.f,0.f}, a1 = a0, a2 = a0, a3 = a0;
        #pragma unroll
        for (int i = 0; i < 8; ++i) {
            a0 = __builtin_elementwise_fma(wr[0][i], hv[i], a0);
            a1 = __builtin_elementwise_fma(wr[1][i], hv[i], a1);
            a2 = __builtin_elementwise_fma(wr[2][i], hv[i], a2);
            a3 = __builtin_elementwise_fma(wr[3][i], hv[i], a3);
        }
        float d0 = (a0.x + a0.y) + (a0.z + a0.w);
        float d1 = (a1.x + a1.y) + (a1.z + a1.w);
        float d2 = (a2.x + a2.y) + (a2.z + a2.w);
        float d3 = (a3.x + a3.y) + (a3.z + a3.w);
        d0 = red_quad(d0);  d1 = red_quad(d1);            // sum the 4 K-slices
        d2 = red_quad(d2);  d3 = red_quad(d3);

        const float gi = d0 + fmaf(x0, wi0_[0], fmaf(x1, wi1_[0], bb_[0]));
        const float gf = d1 + fmaf(x0, wi0_[1], fmaf(x1, wi1_[1], bb_[1]));
        const float gg = d2 + fmaf(x0, wi0_[2], fmaf(x1, wi1_[2], bb_[2]));
        const float go = d3 + fmaf(x0, wi0_[3], fmaf(x1, wi1_[3], bb_[3]));

        // LSTM pointwise (redundant on the 4 group lanes -> h stays in-register)
        const float si = __builtin_amdgcn_rcpf(1.0f + __builtin_amdgcn_exp2f(-L2E * gi));
        const float sf = __builtin_amdgcn_rcpf(1.0f + __builtin_amdgcn_exp2f(-L2E * gf));
        const float so = __builtin_amdgcn_rcpf(1.0f + __builtin_amdgcn_exp2f(-L2E * go));
        const float tg = 1.0f - 2.0f * __builtin_amdgcn_rcpf(__builtin_amdgcn_exp2f(2.0f * L2E * gg) + 1.0f);
        c_reg = sf * c_reg + si * tg;
        const float tc2 = 1.0f - 2.0f * __builtin_amdgcn_rcpf(__builtin_amdgcn_exp2f(2.0f * L2E * c_reg) + 1.0f);
        h_reg = so * tc2;

        if (q == 0) hist[ws * SLOT + 36 * (g >> 5) + (g & 31)] = h_reg;
        phaseG(h_reg, pr ^ 1);                            // x for step k+1

        __syncthreads();
    }

    // Tail: store the final chunk (steps 240..255, ring slots 16..31).
    {
        const int k   = t >> 5;
        const int l32 = t & 31;
        const int w   = 4 * l32;
        const vf4 v = *reinterpret_cast<const vf4*>(
            &hist[(16 + k) * SLOT + 36 * (w >> 5) + (w & 31)]);
        *reinterpret_cast<vf4*>(
            &out[(size_t)(240 + k) * (NB * ND) + b * ND + w]) = v;
    }
}

extern "C" void kernel_launch(void* const* d_in, const int* in_sizes, int n_in,
                              void* d_out, int out_size, void* d_ws, size_t ws_size,
                              hipStream_t stream) {
    const float* enc = (const float*)d_in[0];
    const float* W1w = (const float*)d_in[1];
    const float* W1b = (const float*)d_in[2];
    const float* W2w = (const float*)d_in[3];
    const float* W2b = (const float*)d_in[4];
    const float* Wih = (const float*)d_in[5];
    const float* Whh = (const float*)d_in[6];
    const float* bih = (const float*)d_in[7];
    const float* bhh = (const float*)d_in[8];
    attn_lstm_decoder<<<NB, NT, 0, stream>>>(enc, W1w, W1b, W2w, W2b,
                                             Wih, Whh, bih, bhh, (float*)d_out);
}

// Round 8
// 299.548 us; speedup vs baseline: 3.9016x; 1.0302x over previous
//
#include <hip/hip_runtime.h>

#define NB 256   // batch
#define NS 256   // seq len == number of steps
#define NE 2     // encoder dim
#define ND 128   // decoder dim
#define NT 512   // threads per block (8 waves)
#define NN 16    // Chebyshev nodes/degree for the h -> context map
#define RING 32  // h-history ring depth (2 store chunks of 16)
#define SLOT 144 // padded words per fp32 ring slot (4 slices of 36)
#define SLOTH 160 // padded halfs per f16 ring slot (4 slices of 40)

typedef float vf4 __attribute__((ext_vector_type(4)));
typedef _Float16 f16x2 __attribute__((ext_vector_type(2)));

constexpr float L2E = 1.4426950408889634f;  // log2(e)
constexpr float PI_F = 3.14159265358979323846f;

// Monomial coefficients of Chebyshev T_k: T_k(h) = sum_m CT[k][m] h^m (exact ints).
__device__ const float CT[16][16] = {
 {1,0,0,0,0,0,0,0,0,0,0,0,0,0,0,0},
 {0,1,0,0,0,0,0,0,0,0,0,0,0,0,0,0},
 {-1,0,2,0,0,0,0,0,0,0,0,0,0,0,0,0},
 {0,-3,0,4,0,0,0,0,0,0,0,0,0,0,0,0},
 {1,0,-8,0,8,0,0,0,0,0,0,0,0,0,0,0},
 {0,5,0,-20,0,16,0,0,0,0,0,0,0,0,0,0},
 {-1,0,18,0,-48,0,32,0,0,0,0,0,0,0,0,0},
 {0,-7,0,56,0,-112,0,64,0,0,0,0,0,0,0,0},
 {1,0,-32,0,160,0,-256,0,128,0,0,0,0,0,0,0},
 {0,9,0,-120,0,432,0,-576,0,256,0,0,0,0,0,0},
 {-1,0,50,0,-400,0,1120,0,-1280,0,512,0,0,0,0,0},
 {0,-11,0,220,0,-1232,0,2816,0,-2816,0,1024,0,0,0,0},
 {1,0,-72,0,840,0,-3584,0,6912,0,-6144,0,2048,0,0,0},
 {0,13,0,-364,0,2912,0,-9984,0,16640,0,-13312,0,4096,0,0},
 {-1,0,98,0,-1568,0,9408,0,-26880,0,39424,0,-28672,0,8192,0},
 {0,-15,0,560,0,-6048,0,28800,0,-70400,0,92160,0,-61440,0,16384}};

// DPP add: x + dpp_move(x). All-VALU cross-lane (no LDS pipe, no lgkmcnt).
template <int C>
__device__ __forceinline__ float dppadd(float x) {
    return x + __builtin_bit_cast(float,
        __builtin_amdgcn_update_dpp(0, __builtin_bit_cast(int, x), C, 0xF, 0xF, true));
}
__device__ __forceinline__ float red_quad(float x) {      // sum over each quad
    x = dppadd<0xB1>(x); x = dppadd<0x4E>(x); return x;
}
__device__ __forceinline__ float red_oct(float x) {       // sum over each octet
    x = dppadd<0xB1>(x); x = dppadd<0x4E>(x); x = dppadd<0x141>(x); return x;
}
__device__ __forceinline__ float red_wave64(float x) {    // valid in lane 63
    x = dppadd<0xB1>(x); x = dppadd<0x4E>(x); x = dppadd<0x141>(x);
    x = dppadd<0x140>(x); x = dppadd<0x142>(x); x = dppadd<0x143>(x); return x;
}
__device__ __forceinline__ float red_half32(float x) {    // 32-lane sums
    x = dppadd<0xB1>(x); x = dppadd<0x4E>(x); x = dppadd<0x141>(x);
    x = dppadd<0x140>(x); x = dppadd<0x142>(x); return x;
}
__device__ __forceinline__ float red_grp16(float x) {     // quads hold identical copies:
    // mirrors/bcasts add ONE copy per quad => EXACT sum over 16 quad values.
    x = dppadd<0x141>(x); x = dppadd<0x140>(x);
    x = dppadd<0x142>(x); x = dppadd<0x143>(x); return x;
}

// One block per batch element; 256-step recurrence in-block, ONE barrier/step.
// Attention collapsed (setup) to degree-15 monomial poly, quad-split.
// Gate matvec in f16 via v_dot2_f32_f16 (2 MACs/issue): W_hh as packed f16x2
// in regs, h in a parallel f16 LDS ring. fp32 h ring kept for exact output.
__global__ __launch_bounds__(NT, 2)
void attn_lstm_decoder(const float* __restrict__ enc,   // [B,S,E]
                       const float* __restrict__ W1w,   // [S,S]
                       const float* __restrict__ W1b,   // [S]
                       const float* __restrict__ W2w,   // [S,2S]
                       const float* __restrict__ W2b,   // [S]
                       const float* __restrict__ Wih,   // [4D,E]
                       const float* __restrict__ Whh,   // [4D,D]
                       const float* __restrict__ bih,   // [4D]
                       const float* __restrict__ bhh,   // [4D]
                       float* __restrict__ out)         // [S,B,D]
{
    const int b    = blockIdx.x;
    const int t    = threadIdx.x;
    const int wave = t >> 6;
    const int lane = t & 63;
    const int g    = t >> 2;          // d-index / row group, 0..127
    const int q    = t & 3;           // K-slice quarter / monomial residue
    const bool qb0 = q & 1;
    const bool qb1 = q & 2;
    // setup-only:
    const int half = lane >> 5;
    const int idx  = lane & 31;
    const int jnode = 2 * wave + half;

    __shared__ __align__(16) float    hist[RING * SLOT];    // fp32 h ring (output)
    __shared__ __align__(16) _Float16 hist16[RING * SLOTH]; // f16 h ring (dots)
    __shared__ __align__(16) float xwbuf[2][16];        // 8 waves x float2 partial x
    __shared__ float A2_l[NS];
    __shared__ float g2_l[NS];
    __shared__ float e0_l[NS];
    __shared__ float e1_l[NS];
    __shared__ float Ml[NN * NN];
    __shared__ float2 Pn[NN];
    __shared__ float2 Vl[NN];
    __shared__ float Pm0[NN], Pm1[NN];

    // ---------------- setup (once per block) ----------------
    {
        float v = enc[b * (NS * NE) + t];      // coalesced
        if (t & 1) e1_l[t >> 1] = v; else e0_l[t >> 1] = v;
    }
    if (t < NN * NN) {
        const int mi = t >> 4, mj = t & 15;
        const float w = (mi == 0) ? (1.0f / NN) : (2.0f / NN);
        Ml[t] = w * __cosf((float)(mi * (2 * mj + 1)) * (PI_F / (2 * NN)));
    }
    __syncthreads();

    // w1sum rows and w2term rows: 32 rows per wave (DPP reductions).
    for (int r = 0; r < 32; ++r) {
        const int s = wave * 32 + r;
        float p = W1w[s * NS + lane]       + W1w[s * NS + lane + 64]
                + W1w[s * NS + lane + 128] + W1w[s * NS + lane + 192];
        p = red_wave64(p);
        if (lane == 63) g2_l[s] = p * (2.0f * L2E);
        float qq = 0.0f;
        #pragma unroll
        for (int kk = 0; kk < 8; ++kk) {
            const int c = lane + kk * 64;
            const float ev = (c & 1) ? e1_l[c >> 1] : e0_l[c >> 1];
            qq = fmaf(ev, W2w[s * (2 * NS) + c], qq);
        }
        qq = red_wave64(qq);
        if (lane == 63) A2_l[s] = (qq + W2b[s] + W1b[s]) * (2.0f * L2E);
    }
    __syncthreads();

    // One-time node softmax: F(y_j) for the 16 Chebyshev nodes (2 nodes/wave).
    {
        const float y  = __cosf((float)(2 * jnode + 1) * (PI_F / (2 * NN)));
        const float C2 = -2.0f * L2E;
        float l = 0.0f, p0 = 0.0f, p1 = 0.0f;
        #pragma unroll
        for (int k = 0; k < 8; ++k) {
            const int s = k * 32 + idx;
            const float m1 = fmaf(y, g2_l[s], A2_l[s]);
            const float u  = __builtin_amdgcn_exp2f(m1);
            const float rc = __builtin_amdgcn_rcpf(u + 1.0f);
            const float e  = __builtin_amdgcn_exp2f(rc * C2);
            l += e;
            p0 = fmaf(e, e0_l[s], p0);
            p1 = fmaf(e, e1_l[s], p1);
        }
        l = red_half32(l); p0 = red_half32(p0); p1 = red_half32(p1);
        if ((lane & 31) == 31) {
            const float rl = __builtin_amdgcn_rcpf(l);
            Pn[jnode] = make_float2(p0 * rl, p1 * rl);
        }
    }
    __syncthreads();

    // DCT collapse: V[i] = sum_j M[i][j]*Pn[j], 1/ND folded in.
    if (t < NN) {
        float v0 = 0.0f, v1 = 0.0f;
        #pragma unroll
        for (int j = 0; j < NN; ++j) {
            v0 = fmaf(Ml[t * NN + j], Pn[j].x, v0);
            v1 = fmaf(Ml[t * NN + j], Pn[j].y, v1);
        }
        Vl[t] = make_float2(v0 * (1.0f / ND), v1 * (1.0f / ND));
    }

    // W_hh slices for rows g+128j, K range [32q,32q+32) -> 16 packed f16x2 each.
    f16x2 wr16[4][16];
    float wi0_[4], wi1_[4], bb_[4];
    #pragma unroll
    for (int j = 0; j < 4; ++j) {
        const int r = g + 128 * j;
        const vf4* W4 = reinterpret_cast<const vf4*>(Whh + r * ND + q * 32);
        #pragma unroll
        for (int i = 0; i < 8; ++i) {
            const vf4 w = W4[i];
            wr16[j][2 * i + 0] = f16x2{(_Float16)w.x, (_Float16)w.y};
            wr16[j][2 * i + 1] = f16x2{(_Float16)w.z, (_Float16)w.w};
        }
        wi0_[j] = Wih[r * 2 + 0];
        wi1_[j] = Wih[r * 2 + 1];
        bb_[j]  = bih[r] + bhh[r];
    }

    // zero-init ring slot 31 (input of step 0) in both rings
    if (t < ND) {
        hist[31 * SLOT + 36 * (t >> 5) + (t & 31)] = 0.0f;
        hist16[31 * SLOTH + 40 * (t >> 5) + (t & 31)] = (_Float16)0.0f;
    }
    float h_reg = 0.0f, c_reg = 0.0f;
    __syncthreads();                   // Vl visible

    // Chebyshev -> monomial: Pm[m] = sum_k V[k] * CT[k][m].
    if (t < NN) {
        float s0 = 0.0f, s1 = 0.0f;
        #pragma unroll
        for (int k = 0; k < NN; ++k) {
            s0 = fmaf(Vl[k].x, CT[k][t], s0);
            s1 = fmaf(Vl[k].y, CT[k][t], s1);
        }
        Pm0[t] = s0; Pm1[t] = s1;
    }
    __syncthreads();                   // Pm visible

    // Per-lane residue-class coefficients: G_e(h) = sum_q h^q * Q_q(h^4).
    float Q0[4], Q1[4];
    #pragma unroll
    for (int i = 0; i < 4; ++i) { Q0[i] = Pm0[4 * i + q]; Q1[i] = Pm1[4 * i + q]; }

    // phaseG: quad-split monomial eval; red_quad reassembles G(h), then
    // mirror-reduce over the 16 quads. lane63 writes this wave's partial.
    auto phaseG = [&](float h, int pw) {
        const float h2 = h * h;
        const float h3 = h2 * h;
        const float h4 = h2 * h2;
        const float hq = qb1 ? (qb0 ? h3 : h2) : (qb0 ? h : 1.0f);
        float a0 = fmaf(Q0[3], h4, Q0[2]);
        a0 = fmaf(a0, h4, Q0[1]);
        a0 = fmaf(a0, h4, Q0[0]);
        float a1 = fmaf(Q1[3], h4, Q1[2]);
        a1 = fmaf(a1, h4, Q1[1]);
        a1 = fmaf(a1, h4, Q1[0]);
        a0 *= hq;
        a1 *= hq;
        a0 = red_quad(a0);  a1 = red_quad(a1);     // reassemble G(h_g)
        a0 = red_grp16(a0); a1 = red_grp16(a1);    // sum over the wave's 16 g
        if (lane == 63) {
            xwbuf[pw][2 * wave + 0] = a0;
            xwbuf[pw][2 * wave + 1] = a1;
        }
    };

    phaseG(0.0f, 0);       // x for step 0 (h = 0)
    __syncthreads();

    // ---------------- the recurrence (ONE barrier per step) ----------------
    for (int step = 0; step < NS; ++step) {
        const int pr = step & 1;
        const int rs = (step + RING - 1) & (RING - 1);   // slot holding h(step-1)
        const int ws = step & (RING - 1);                // slot for h(step)

        // Front-load all LDS reads so their latency overlaps the chunk store.
        float2 xv = *reinterpret_cast<const float2*>(&xwbuf[pr][2 * (lane & 7)]);
        const int4* hb = reinterpret_cast<const int4*>(&hist16[rs * SLOTH + q * 40]);
        int hw[16];
        #pragma unroll
        for (int i = 0; i < 4; ++i) {
            const int4 v = hb[i];                        // b128, banks 0/20/8/28
            hw[4 * i + 0] = v.x; hw[4 * i + 1] = v.y;
            hw[4 * i + 2] = v.z; hw[4 * i + 3] = v.w;
        }

        // Chunk store (every 16 steps, at step TOP): steps step-16..step-1.
        if ((step & 15) == 0 && step > 0) {
            const int sb  = (step - 16) & (RING - 1);
            const int k   = t >> 5;
            const int l32 = t & 31;
            const int w   = 4 * l32;
            const vf4 v = *reinterpret_cast<const vf4*>(
                &hist[(sb + k) * SLOT + 36 * (w >> 5) + (w & 31)]);
            *reinterpret_cast<vf4*>(
                &out[(size_t)(step - 16 + k) * (NB * ND) + b * ND + w]) = v;
        }

        float x0 = red_oct(xv.x);
        float x1 = red_oct(xv.y);

        // Gate dots over this thread's 32-element h slice: 16 fdot2 per row,
        // 2 independent accumulator chains per row for ILP.
        float d0a = 0.f, d0b = 0.f, d1a = 0.f, d1b = 0.f;
        float d2a = 0.f, d2b = 0.f, d3a = 0.f, d3b = 0.f;
        #pragma unroll
        for (int i = 0; i < 8; ++i) {
            const f16x2 ha = __builtin_bit_cast(f16x2, hw[2 * i + 0]);
            const f16x2 hbv = __builtin_bit_cast(f16x2, hw[2 * i + 1]);
            d0a = __builtin_amdgcn_fdot2(wr16[0][2 * i + 0], ha,  d0a, false);
            d0b = __builtin_amdgcn_fdot2(wr16[0][2 * i + 1], hbv, d0b, false);
            d1a = __builtin_amdgcn_fdot2(wr16[1][2 * i + 0], ha,  d1a, false);
            d1b = __builtin_amdgcn_fdot2(wr16[1][2 * i + 1], hbv, d1b, false);
            d2a = __builtin_amdgcn_fdot2(wr16[2][2 * i + 0], ha,  d2a, false);
            d2b = __builtin_amdgcn_fdot2(wr16[2][2 * i + 1], hbv, d2b, false);
            d3a = __builtin_amdgcn_fdot2(wr16[3][2 * i + 0], ha,  d3a, false);
            d3b = __builtin_amdgcn_fdot2(wr16[3][2 * i + 1], hbv, d3b, false);
        }
        float d0 = d0a + d0b, d1 = d1a + d1b;
        float d2 = d2a + d2b, d3 = d3a + d3b;
        d0 = red_quad(d0);  d1 = red_quad(d1);            // sum the 4 K-slices
        d2 = red_quad(d2);  d3 = red_quad(d3);

        const float gi = d0 + fmaf(x0, wi0_[0], fmaf(x1, wi1_[0], bb_[0]));
        const float gf = d1 + fmaf(x0, wi0_[1], fmaf(x1, wi1_[1], bb_[1]));
        const float gg = d2 + fmaf(x0, wi0_[2], fmaf(x1, wi1_[2], bb_[2]));
        const float go = d3 + fmaf(x0, wi0_[3], fmaf(x1, wi1_[3], bb_[3]));

        // LSTM pointwise (redundant on the 4 group lanes -> h stays in-register)
        const float si = __builtin_amdgcn_rcpf(1.0f + __builtin_amdgcn_exp2f(-L2E * gi));
        const float sf = __builtin_amdgcn_rcpf(1.0f + __builtin_amdgcn_exp2f(-L2E * gf));
        const float so = __builtin_amdgcn_rcpf(1.0f + __builtin_amdgcn_exp2f(-L2E * go));
        const float tg = 1.0f - 2.0f * __builtin_amdgcn_rcpf(__builtin_amdgcn_exp2f(2.0f * L2E * gg) + 1.0f);
        c_reg = sf * c_reg + si * tg;
        const float tc2 = 1.0f - 2.0f * __builtin_amdgcn_rcpf(__builtin_amdgcn_exp2f(2.0f * L2E * c_reg) + 1.0f);
        h_reg = so * tc2;

        if (q == 0) {
            hist[ws * SLOT + 36 * (g >> 5) + (g & 31)] = h_reg;
            hist16[ws * SLOTH + 40 * (g >> 5) + (g & 31)] = (_Float16)h_reg;
        }
        phaseG(h_reg, pr ^ 1);                            // x for step k+1

        __syncthreads();
    }

    // Tail: store the final chunk (steps 240..255, ring slots 16..31).
    {
        const int k   = t >> 5;
        const int l32 = t & 31;
        const int w   = 4 * l32;
        const vf4 v = *reinterpret_cast<const vf4*>(
            &hist[(16 + k) * SLOT + 36 * (w >> 5) + (w & 31)]);
        *reinterpret_cast<vf4*>(
            &out[(size_t)(240 + k) * (NB * ND) + b * ND + w]) = v;
    }
}

extern "C" void kernel_launch(void* const* d_in, const int* in_sizes, int n_in,
                              void* d_out, int out_size, void* d_ws, size_t ws_size,
                              hipStream_t stream) {
    const float* enc = (const float*)d_in[0];
    const float* W1w = (const float*)d_in[1];
    const float* W1b = (const float*)d_in[2];
    const float* W2w = (const float*)d_in[3];
    const float* W2b = (const float*)d_in[4];
    const float* Wih = (const float*)d_in[5];
    const float* Whh = (const float*)d_in[6];
    const float* bih = (const float*)d_in[7];
    const float* bhh = (const float*)d_in[8];
    attn_lstm_decoder<<<NB, NT, 0, stream>>>(enc, W1w, W1b, W2w, W2b,
                                             Wih, Whh, bih, bhh, (float*)d_out);
}